// Round 12
// baseline (489.745 us; speedup 1.0000x reference)
//
#include <hip/hip_runtime.h>
#include <math.h>

#define NP 100000
#define KN 16
#define DIM 64
constexpr float BN_EPS_F = 1e-5f;
constexpr double MS = (double)NP * (double)KN;   // 1,600,000 samples

typedef __attribute__((ext_vector_type(8))) short short8;
typedef __attribute__((ext_vector_type(4))) float f32x4;
typedef __attribute__((ext_vector_type(2))) unsigned uint32x2;
typedef __attribute__((ext_vector_type(4))) unsigned uint32x4;

// ---- workspace layout (BYTE offsets) ----
constexpr size_t B_S1  = 0;        // 10 dbl
constexpr size_t B_PWE = 128;      // 64 * float4
constexpr size_t B_S2  = 1152;     // 128 dbl
constexpr size_t B_BN2 = 2176;     // 128 f
constexpr size_t B_ZSE = 2688;     // 64 f
constexpr size_t B_ZSB = 2944;     // 64 f
constexpr size_t B_PFS = 3200;     // 64 f
constexpr size_t B_PTS = 4096;                                  // f32 [NP+1][3]
constexpr size_t B_Q   = 1204224;                               // bf16 [NP][64]
constexpr size_t B_U   = B_Q + (size_t)NP * DIM * 2;            // bf16 [NP+1][64]: v+pf
constexpr size_t B_KK  = B_U + (size_t)(NP + 1) * DIM * 2;      // tier1: u32 KP; tier2: bf16 K
// tier 1: KP u32 [(NP+1)][64]
constexpr size_t B_Z1   = B_KK + (size_t)(NP + 1) * DIM * 4;
constexpr size_t B_END1 = B_Z1 + (size_t)NP * 2048;             // 257,204,608
// tier 2: K bf16 [(NP+1)][64]
constexpr size_t B_Z2   = B_KK + (size_t)(NP + 1) * DIM * 2;
constexpr size_t B_END2 = B_Z2 + (size_t)NP * 2048;             // 244,404,480 (proven fits)

__device__ __forceinline__ ushort f2bf(float f) {
  union { float f; unsigned u; } v; v.f = f;
  unsigned u = v.u + 0x7fffu + ((v.u >> 16) & 1u);   // RNE
  return (ushort)(u >> 16);
}
__device__ __forceinline__ float bf2f(ushort b) {
  union { unsigned u; float f; } v; v.u = ((unsigned)b) << 16;
  return v.f;
}
__device__ __forceinline__ float u2f(unsigned u) {
  union { unsigned u; float f; } v; v.u = u; return v.f;
}

// hoist a [64][64] row-major weight into 8 bf16x8 fragments (B-operand)
__device__ __forceinline__ void load_wfrags(const float* __restrict__ ww, int lane,
                                            short8 wf[4][2]) {
  int co = lane & 15, g = lane >> 4;
#pragma unroll
  for (int tn = 0; tn < 4; ++tn)
#pragma unroll
    for (int kk = 0; kk < 2; ++kk) {
      const float* p = ww + (size_t)(co + 16 * tn) * DIM + kk * 32 + g * 8;
      short8 f;
#pragma unroll
      for (int j = 0; j < 8; ++j) f[j] = (short)f2bf(p[j]);
      wf[tn][kk] = f;
    }
}

__device__ __forceinline__ short8 pack_bf8(float4 a, float4 b) {
  short8 r;
  r[0] = (short)f2bf(a.x); r[1] = (short)f2bf(a.y);
  r[2] = (short)f2bf(a.z); r[3] = (short)f2bf(a.w);
  r[4] = (short)f2bf(b.x); r[5] = (short)f2bf(b.y);
  r[6] = (short)f2bf(b.z); r[7] = (short)f2bf(b.w);
  return r;
}

__global__ void k_init(char* __restrict__ wsb) {
  int t = threadIdx.x;
  double* s1 = (double*)(wsb + B_S1);
  double* s2 = (double*)(wsb + B_S2);
  if (t < 10) s1[t] = 0.0;
  if (t < 128) s2[t] = 0.0;
  if (t < 32)
    ((unsigned*)(wsb + B_U))[(size_t)NP * 32 + t] = 0u;   // u pad row (substituted anyway)
}

// padded f32 [NP+1][3] point table; row NP = (1e6,1e6,1e6)
__global__ __launch_bounds__(256) void k_pts(const float* __restrict__ pts,
                                             char* __restrict__ wsb) {
  int t = blockIdx.x * 256 + threadIdx.x;
  float* p3 = (float*)(wsb + B_PTS);
  if (t < NP * 3) p3[t] = pts[t];
  else if (t < NP * 3 + 3) p3[t] = 1e6f;
}

// point moments (9 doubles) + shadow count
__global__ __launch_bounds__(256) void k_stats1(const int* __restrict__ nbr,
    char* __restrict__ wsb) {
  const float* p3 = (const float*)(wsb + B_PTS);
  double a[10] = {0, 0, 0, 0, 0, 0, 0, 0, 0, 0};
  int stride = gridDim.x * blockDim.x;
  for (int e = blockIdx.x * 256 + threadIdx.x; e < NP * KN; e += stride) {
    int idx = nbr[e];
    const float* pr = p3 + (size_t)idx * 3;
    float x = pr[0], y = pr[1], z = pr[2];
    a[9] += (idx >= NP) ? 1.0 : 0.0;
    a[0] += x; a[1] += y; a[2] += z;
    a[3] += (double)x * x; a[4] += (double)x * y; a[5] += (double)x * z;
    a[6] += (double)y * y; a[7] += (double)y * z; a[8] += (double)z * z;
  }
  __shared__ double red[256];
  double* s1 = (double*)(wsb + B_S1);
  for (int j = 0; j < 10; ++j) {
    red[threadIdx.x] = a[j];
    __syncthreads();
    for (int s = 128; s > 0; s >>= 1) {
      if (threadIdx.x < s) red[threadIdx.x] += red[threadIdx.x + s];
      __syncthreads();
    }
    if (threadIdx.x == 0) atomicAdd(&s1[j], red[0]);
    __syncthreads();
  }
}

// fold BN1 into affine on xyz
__global__ void k_fold1(const float* __restrict__ pw, const float* __restrict__ pb,
                        const float* __restrict__ pg, const float* __restrict__ pbeta,
                        char* __restrict__ wsb) {
  int c = threadIdx.x;
  if (c >= DIM) return;
  double* s1 = (double*)(wsb + B_S1);
  double inv = 1.0 / MS;
  double m0 = s1[0] * inv, m1 = s1[1] * inv, m2 = s1[2] * inv;
  double C00 = s1[3] * inv - m0 * m0, C01 = s1[4] * inv - m0 * m1;
  double C02 = s1[5] * inv - m0 * m2, C11 = s1[6] * inv - m1 * m1;
  double C12 = s1[7] * inv - m1 * m2, C22 = s1[8] * inv - m2 * m2;
  double w0 = pw[c * 3], w1 = pw[c * 3 + 1], w2 = pw[c * 3 + 2];
  double mean = w0 * m0 + w1 * m1 + w2 * m2 + (double)pb[c];
  double var = w0 * w0 * C00 + w1 * w1 * C11 + w2 * w2 * C22
             + 2.0 * (w0 * w1 * C01 + w0 * w2 * C02 + w1 * w2 * C12);
  if (var < 0.0) var = 0.0;
  double a = (double)pg[c] / sqrt(var + (double)BN_EPS_F);
  float4 o;
  o.x = (float)(w0 * a); o.y = (float)(w1 * a); o.z = (float)(w2 * a);
  o.w = (float)(((double)pb[c] - mean) * a + (double)pbeta[c]);
  ((float4*)(wsb + B_PWE))[c] = o;
}

// exact + bf16-path shadow w_lin; exact fp32 shadow pf; pad row of KK table
__global__ void k_shadow(const float* __restrict__ ww, const float* __restrict__ wb,
                         char* __restrict__ wsb, int kpmode) {
  __shared__ float pfs[64], pfb[64];
  int c = threadIdx.x;
  if (c >= DIM) return;
  float4 pwe = ((const float4*)(wsb + B_PWE))[c];
  float pf = fmaxf(fmaf(pwe.x, 1e6f, fmaf(pwe.y, 1e6f, fmaf(pwe.z, 1e6f, pwe.w))), 0.f);
  pfs[c] = pf;
  pfb[c] = bf2f(f2bf(pf));
  ((float*)(wsb + B_PFS))[c] = pf;
  if (kpmode)
    ((unsigned*)(wsb + B_KK))[(size_t)NP * DIM + c] = ((unsigned)f2bf(pf) << 16);  // k=0
  else
    ((ushort*)(wsb + B_KK))[(size_t)NP * DIM + c] = 0;                             // k=0
  __syncthreads();
  double ze = (double)wb[c], zb = (double)wb[c];
  for (int i = 0; i < DIM; ++i) {
    float w = ww[c * DIM + i];
    ze += (double)pfs[i] * (double)w;
    zb += (double)pfb[i] * (double)bf2f(f2bf(w));
  }
  ((float*)(wsb + B_ZSE))[c] = (float)ze;
  ((float*)(wsb + B_ZSB))[c] = (float)zb;
}

// MFMA q/k/u builder: wave per 16-point tile
template<bool KPMODE>
__global__ __launch_bounds__(256, 2) void k_qkv_mfma(const float* __restrict__ feats,
    const float* __restrict__ qw, const float* __restrict__ qb,
    const float* __restrict__ kw, const float* __restrict__ kb,
    const float* __restrict__ vw, const float* __restrict__ vb,
    char* __restrict__ wsb) {
  int tid = threadIdx.x, wid = tid >> 6, lane = tid & 63;
  int co = lane & 15, g = lane >> 4;
  short8 wfq[4][2], wfk[4][2], wfv[4][2];
  load_wfrags(qw, lane, wfq);
  load_wfrags(kw, lane, wfk);
  load_wfrags(vw, lane, wfv);
  float bq[4], bk[4], bv[4];
  float4 pwe4[4];
#pragma unroll
  for (int tn = 0; tn < 4; ++tn) {
    bq[tn] = qb[co + 16 * tn];
    bk[tn] = kb[co + 16 * tn];
    bv[tn] = vb[co + 16 * tn];
    pwe4[tn] = ((const float4*)(wsb + B_PWE))[co + 16 * tn];
  }
  const float* p3 = (const float*)(wsb + B_PTS);
  ushort* qt = (ushort*)(wsb + B_Q);
  ushort* ut = (ushort*)(wsb + B_U);
  ushort* kt = (ushort*)(wsb + B_KK);
  unsigned* kpt = (unsigned*)(wsb + B_KK);
  const int NT = NP / 16;   // 6250
  for (int t = blockIdx.x * 4 + wid; t < NT; t += gridDim.x * 4) {
    const float* fr = feats + ((size_t)t * 16 + co) * DIM + g * 8;
    float4 f0 = *(const float4*)fr;
    float4 f1 = *(const float4*)(fr + 4);
    float4 f2 = *(const float4*)(fr + 32);
    float4 f3 = *(const float4*)(fr + 36);
    short8 a0 = pack_bf8(f0, f1);
    short8 a1 = pack_bf8(f2, f3);
    int nb = t * 16 + g * 4;
    float px[4], py[4], pz[4];
#pragma unroll
    for (int r = 0; r < 4; ++r) {
      const float* pr = p3 + (size_t)(nb + r) * 3;
      px[r] = pr[0]; py[r] = pr[1]; pz[r] = pr[2];
    }
    float pf[4][4];
#pragma unroll
    for (int tn = 0; tn < 4; ++tn)
#pragma unroll
      for (int r = 0; r < 4; ++r)
        pf[tn][r] = fmaxf(fmaf(pwe4[tn].x, px[r], fmaf(pwe4[tn].y, py[r],
                          fmaf(pwe4[tn].z, pz[r], pwe4[tn].w))), 0.f);
#pragma unroll
    for (int tn = 0; tn < 4; ++tn) {
      f32x4 acc = {bq[tn], bq[tn], bq[tn], bq[tn]};
      acc = __builtin_amdgcn_mfma_f32_16x16x32_bf16(a0, wfq[tn][0], acc, 0, 0, 0);
      acc = __builtin_amdgcn_mfma_f32_16x16x32_bf16(a1, wfq[tn][1], acc, 0, 0, 0);
#pragma unroll
      for (int r = 0; r < 4; ++r)
        qt[(size_t)(nb + r) * DIM + co + 16 * tn] = f2bf(acc[r]);
    }
#pragma unroll
    for (int tn = 0; tn < 4; ++tn) {
      f32x4 acc = {bk[tn], bk[tn], bk[tn], bk[tn]};
      acc = __builtin_amdgcn_mfma_f32_16x16x32_bf16(a0, wfk[tn][0], acc, 0, 0, 0);
      acc = __builtin_amdgcn_mfma_f32_16x16x32_bf16(a1, wfk[tn][1], acc, 0, 0, 0);
#pragma unroll
      for (int r = 0; r < 4; ++r) {
        if (KPMODE)
          kpt[(size_t)(nb + r) * DIM + co + 16 * tn] =
              ((unsigned)f2bf(pf[tn][r]) << 16) | (unsigned)f2bf(acc[r]);
        else
          kt[(size_t)(nb + r) * DIM + co + 16 * tn] = f2bf(acc[r]);
      }
    }
#pragma unroll
    for (int tn = 0; tn < 4; ++tn) {
      f32x4 acc = {bv[tn], bv[tn], bv[tn], bv[tn]};
      acc = __builtin_amdgcn_mfma_f32_16x16x32_bf16(a0, wfv[tn][0], acc, 0, 0, 0);
      acc = __builtin_amdgcn_mfma_f32_16x16x32_bf16(a1, wfv[tn][1], acc, 0, 0, 0);
#pragma unroll
      for (int r = 0; r < 4; ++r)
        ut[(size_t)(nb + r) * DIM + co + 16 * tn] = f2bf(acc[r] + pf[tn][r]);
    }
  }
}

// ---- pipeline macros (per-lane vector loads only) ----
#define LOADN(SET, nn) {                                                      \
  const int4* p4_ = (const int4*)(nbr + (size_t)(nn) * KN);                   \
  int4 b0_ = p4_[0], b1_ = p4_[1], b2_ = p4_[2], b3_ = p4_[3];                \
  i##SET[0] = b0_.x; i##SET[1] = b0_.y; i##SET[2] = b0_.z; i##SET[3] = b0_.w; \
  i##SET[4] = b1_.x; i##SET[5] = b1_.y; i##SET[6] = b1_.z; i##SET[7] = b1_.w; \
  i##SET[8] = b2_.x; i##SET[9] = b2_.y; i##SET[10]= b2_.z; i##SET[11]= b2_.w; \
  i##SET[12]= b3_.x; i##SET[13]= b3_.y; i##SET[14]= b3_.z; i##SET[15]= b3_.w; }

// gather (pf,k) -> packed u32.  Tier1: one u32 gather.  Tier2: k gather + inline pf.
#define S2_LOADG(SET, nn) {                                                   \
  if constexpr (KPMODE) {                                                     \
    _Pragma("unroll") for (int k = 0; k < KN; ++k)                            \
      kp##SET[k] = kpt[(size_t)i##SET[k] * DIM + c];                          \
  } else {                                                                    \
    _Pragma("unroll") for (int k = 0; k < KN; ++k) {                          \
      int ik_ = i##SET[k];                                                    \
      unsigned kv_ = kt[(size_t)ik_ * DIM + c];                               \
      const float* pr_ = p3 + (size_t)ik_ * 3;                                \
      float px_ = pr_[0], py_ = pr_[1], pz_ = pr_[2];                         \
      float pf_ = fmaxf(fmaf(pwe.x, px_, fmaf(pwe.y, py_,                     \
                        fmaf(pwe.z, pz_, pwe.w))), 0.f);                      \
      kp##SET[k] = ((unsigned)f2bf(pf_) << 16) | kv_;                         \
    }                                                                         \
  }                                                                           \
  q##SET = bf2f(qt[(size_t)(nn) * DIM + c]); }

// h-build + MFMA + stats + transposed z store ([n][co][k] bf16) — NT stores
#define S2_COMPUTE(SET, nn) {                                                 \
  _Pragma("unroll") for (int k = 0; k < KN; ++k) {                            \
    float kg_ = u2f(kp##SET[k] << 16);                                        \
    float pf_ = u2f(kp##SET[k] & 0xffff0000u);                                \
    hw[k * 64 + (c ^ ((k & 7) << 3))] = f2bf(fmaf(kg_, q##SET, pf_));         \
  }                                                                           \
  __builtin_amdgcn_wave_barrier();                                            \
  short8 a0_ = *(short8*)&hw[aoff0];                                          \
  short8 a1_ = *(short8*)&hw[aoff1];                                          \
  char* zr_ = ztc + (size_t)(nn) * 2048 + g * 8;                              \
  _Pragma("unroll") for (int tn = 0; tn < 4; ++tn) {                          \
    f32x4 acc_ = {wbv[tn], wbv[tn], wbv[tn], wbv[tn]};                        \
    acc_ = __builtin_amdgcn_mfma_f32_16x16x32_bf16(a0_, wf[tn][0], acc_,0,0,0);\
    acc_ = __builtin_amdgcn_mfma_f32_16x16x32_bf16(a1_, wf[tn][1], acc_,0,0,0);\
    _Pragma("unroll") for (int r = 0; r < 4; ++r) {                           \
      float zv_ = acc_[r];                                                    \
      s[tn] += zv_; ssq[tn] = fmaf(zv_, zv_, ssq[tn]); }                      \
    uint32x2 w_;                                                              \
    w_.x = (unsigned)f2bf(acc_[0]) | ((unsigned)f2bf(acc_[1]) << 16);         \
    w_.y = (unsigned)f2bf(acc_[2]) | ((unsigned)f2bf(acc_[3]) << 16);         \
    __builtin_nontemporal_store(w_,                                           \
        (uint32x2*)(zr_ + ((lane & 15) + 16 * tn) * 32));                     \
  }                                                                           \
  __builtin_amdgcn_wave_barrier(); }

// BN2 stats via MFMA + z store.  grid MUST be 3125 x 256 (8 points/wave).
template<bool KPMODE>
__global__ __launch_bounds__(256) void k_stats2(const int* __restrict__ nbr,
    const float* __restrict__ ww, const float* __restrict__ wbias,
    char* __restrict__ wsb, char* __restrict__ ztc) {
  __shared__ ushort hl[4][16 * 64];
  __shared__ float sred[4][64], ssred[4][64];
  int tid = threadIdx.x, wid = tid >> 6, lane = tid & 63, c = lane;
  short8 wf[4][2];
  load_wfrags(ww, lane, wf);
  float wbv[4];
#pragma unroll
  for (int tn = 0; tn < 4; ++tn) wbv[tn] = wbias[(lane & 15) + 16 * tn];
  const ushort* qt = (const ushort*)(wsb + B_Q);
  const ushort* kt = (const ushort*)(wsb + B_KK);
  const unsigned* kpt = (const unsigned*)(wsb + B_KK);
  const float* p3 = (const float*)(wsb + B_PTS);
  float4 pwe = ((const float4*)(wsb + B_PWE))[c];
  ushort* hw = hl[wid];
  int row = lane & 15, g = lane >> 4;
  int aoff0 = row * 64 + ((g * 8) ^ ((row & 7) << 3));
  int aoff1 = row * 64 + ((32 + g * 8) ^ ((row & 7) << 3));
  float s[4] = {0, 0, 0, 0}, ssq[4] = {0, 0, 0, 0};
  const int S = gridDim.x * 4;     // 12500
  int n = blockIdx.x * 4 + wid;

  int iA[KN], iB[KN];
  unsigned kpA[KN], kpB[KN];
  float qA, qB;

  LOADN(A, n)
  LOADN(B, n + S)
  S2_LOADG(A, n)
  for (int it = 0; it < 4; ++it) {
    S2_LOADG(B, n + S)
    if (it < 3) LOADN(A, n + 2 * S)
    S2_COMPUTE(A, n)
    if (it < 3) { S2_LOADG(A, n + 2 * S) LOADN(B, n + 3 * S) }
    S2_COMPUTE(B, n + S)
    n += 2 * S;
  }
#pragma unroll
  for (int t = 0; t < 4; ++t) {
    s[t] += __shfl_xor(s[t], 16);    s[t] += __shfl_xor(s[t], 32);
    ssq[t] += __shfl_xor(ssq[t], 16); ssq[t] += __shfl_xor(ssq[t], 32);
  }
  if (lane < 16) {
#pragma unroll
    for (int t = 0; t < 4; ++t) { sred[wid][lane + 16 * t] = s[t]; ssred[wid][lane + 16 * t] = ssq[t]; }
  }
  __syncthreads();
  if (tid < DIM) {
    double SS0 = 0.0, SS1 = 0.0;
    for (int w = 0; w < 4; ++w) { SS0 += (double)sred[w][tid]; SS1 += (double)ssred[w][tid]; }
    double* s2 = (double*)(wsb + B_S2);
    atomicAdd(&s2[tid], SS0);
    atomicAdd(&s2[DIM + tid], SS1);
  }
}

__global__ void k_fold2(const float* __restrict__ wg, const float* __restrict__ wbeta,
                        char* __restrict__ wsb) {
  int c = threadIdx.x;
  if (c >= DIM) return;
  double* s2 = (double*)(wsb + B_S2);
  double* s1 = (double*)(wsb + B_S1);
  double nsh = s1[9];
  double zse = (double)((float*)(wsb + B_ZSE))[c];
  double zsb = (double)((float*)(wsb + B_ZSB))[c];
  double S  = s2[c] + nsh * (zse - zsb);
  double SS = s2[DIM + c] + nsh * (zse * zse - zsb * zsb);
  double mean = S / MS;
  double var = SS / MS - mean * mean;
  if (var < 0.0) var = 0.0;
  double a = (double)wg[c] / sqrt(var + (double)BN_EPS_F);
  ((float*)(wsb + B_BN2))[c] = (float)a;
  ((float*)(wsb + B_BN2))[DIM + c] = (float)((double)wbeta[c] - mean * a);
}

// ---- streaming final: NT z reads + u gather + softmax + NT out. grid 3125x256. ----
#define FS_LOADG(SET, nn) {                                                   \
  const char* zr_ = ztc + (size_t)(nn) * 2048 + c * 32;                       \
  *(uint32x4*)&zz##SET[0] = __builtin_nontemporal_load((const uint32x4*)zr_); \
  *(uint32x4*)&zz##SET[4] =                                                   \
      __builtin_nontemporal_load((const uint32x4*)(zr_ + 16));                \
  _Pragma("unroll") for (int k = 0; k < KN; ++k)                              \
    uv##SET[k] = ut[(size_t)i##SET[k] * DIM + c];                             \
  sh##SET = 0u;                                                               \
  _Pragma("unroll") for (int k = 0; k < KN; ++k)                              \
    sh##SET |= (unsigned)(i##SET[k] >= NP) << k; }

#define FS_COMPUTE(SET, nn) {                                                 \
  float lg_[KN];                                                              \
  float m_ = 0.f;                                                             \
  _Pragma("unroll") for (int k = 0; k < KN; ++k) {                            \
    float lin_ = bf2f((ushort)(zz##SET[k >> 1] >> ((k & 1) * 16)));           \
    if ((sh##SET >> k) & 1u) lin_ = zsec;                                     \
    float t_ = fmaxf(fmaf(lin_, fsc, fsh), 0.f);                              \
    lg_[k] = t_; m_ = fmaxf(m_, t_); }                                        \
  float se_ = 0.f;                                                            \
  _Pragma("unroll") for (int k = 0; k < KN; ++k) {                            \
    float e_ = __expf(lg_[k] - m_); lg_[k] = e_; se_ += e_; }                 \
  float rs_ = 1.0f / se_;                                                     \
  float att_ = 0.f;                                                           \
  _Pragma("unroll") for (int k = 0; k < KN; ++k) {                            \
    float u_ = ((sh##SET >> k) & 1u) ? pfsec : bf2f(uv##SET[k]);              \
    att_ = fmaf(u_, lg_[k] * rs_, att_); }                                    \
  __builtin_nontemporal_store(att_, out + (size_t)(nn) * DIM + c); }

__global__ __launch_bounds__(256, 4) void k_final_str(const int* __restrict__ nbr,
    const char* __restrict__ wsb, const char* __restrict__ ztc,
    float* __restrict__ out) {
  int tid = threadIdx.x, wid = tid >> 6, c = tid & 63;
  const ushort* ut = (const ushort*)(wsb + B_U);
  const float* bn2 = (const float*)(wsb + B_BN2);
  float fsc = bn2[c], fsh = bn2[DIM + c];
  float zsec = ((const float*)(wsb + B_ZSE))[c];
  float pfsec = ((const float*)(wsb + B_PFS))[c];
  const int S = gridDim.x * 4;     // 12500
  int n = blockIdx.x * 4 + wid;

  int iA[KN], iB[KN];
  unsigned zzA[8] __attribute__((aligned(16)));
  unsigned zzB[8] __attribute__((aligned(16)));
  ushort uvA[KN], uvB[KN];
  unsigned shA, shB;

  LOADN(A, n)
  LOADN(B, n + S)
  FS_LOADG(A, n)
  for (int it = 0; it < 4; ++it) {
    FS_LOADG(B, n + S)
    if (it < 3) LOADN(A, n + 2 * S)
    FS_COMPUTE(A, n)
    if (it < 3) { FS_LOADG(A, n + 2 * S) LOADN(B, n + 3 * S) }
    FS_COMPUTE(B, n + S)
    n += 2 * S;
  }
}

extern "C" void kernel_launch(void* const* d_in, const int* in_sizes, int n_in,
                              void* d_out, int out_size, void* d_ws, size_t ws_size,
                              hipStream_t stream) {
  const float* pts   = (const float*)d_in[0];
  const int*   nbr   = (const int*)d_in[1];
  const float* feats = (const float*)d_in[2];
  const float* qw = (const float*)d_in[3];  const float* qb = (const float*)d_in[4];
  const float* kw = (const float*)d_in[5];  const float* kb = (const float*)d_in[6];
  const float* vw = (const float*)d_in[7];  const float* vb = (const float*)d_in[8];
  const float* pw = (const float*)d_in[9];  const float* pb = (const float*)d_in[10];
  const float* pg = (const float*)d_in[11]; const float* pbeta = (const float*)d_in[12];
  const float* www = (const float*)d_in[13]; const float* wb = (const float*)d_in[14];
  const float* wg  = (const float*)d_in[15]; const float* wbeta = (const float*)d_in[16];
  char* wsb = (char*)d_ws;
  float* out = (float*)d_out;

  const bool kpmode = (ws_size >= B_END1);      // tier 1 if the workspace allows
  char* zt = wsb + (kpmode ? B_Z1 : B_Z2);

  hipLaunchKernelGGL(k_init,   dim3(1),    dim3(256), 0, stream, wsb);
  hipLaunchKernelGGL(k_pts,    dim3(1173), dim3(256), 0, stream, pts, wsb);
  hipLaunchKernelGGL(k_stats1, dim3(2048), dim3(256), 0, stream, nbr, wsb);
  hipLaunchKernelGGL(k_fold1,  dim3(1),    dim3(64),  0, stream, pw, pb, pg, pbeta, wsb);
  hipLaunchKernelGGL(k_shadow, dim3(1),    dim3(64),  0, stream, www, wb, wsb, (int)kpmode);
  if (kpmode) {
    hipLaunchKernelGGL((k_qkv_mfma<true>), dim3(1024), dim3(256), 0, stream,
                       feats, qw, qb, kw, kb, vw, vb, wsb);
    hipLaunchKernelGGL((k_stats2<true>),   dim3(3125), dim3(256), 0, stream,
                       nbr, www, wb, wsb, zt);
  } else {
    hipLaunchKernelGGL((k_qkv_mfma<false>), dim3(1024), dim3(256), 0, stream,
                       feats, qw, qb, kw, kb, vw, vb, wsb);
    hipLaunchKernelGGL((k_stats2<false>),   dim3(3125), dim3(256), 0, stream,
                       nbr, www, wb, wsb, zt);
  }
  hipLaunchKernelGGL(k_fold2, dim3(1), dim3(64), 0, stream, wg, wbeta, wsb);
  hipLaunchKernelGGL(k_final_str, dim3(3125), dim3(256), 0, stream, nbr, wsb, zt, out);
}

// Round 13
// 330.751 us; speedup vs baseline: 1.4807x; 1.4807x over previous
//
#include <hip/hip_runtime.h>
#include <math.h>

#define NP 100000
#define KN 16
#define DIM 64
constexpr float BN_EPS_F = 1e-5f;
constexpr double MS = (double)NP * (double)KN;   // 1,600,000 samples

typedef __attribute__((ext_vector_type(8))) short short8;
typedef __attribute__((ext_vector_type(4))) float f32x4;

// ---- workspace layout (BYTE offsets) ----  total ~52.4 MB (always fits)
constexpr size_t B_S1  = 0;        // 10 dbl
constexpr size_t B_PWE = 128;      // 64 * float4
constexpr size_t B_S2  = 1152;     // 128 dbl
constexpr size_t B_BN2 = 2176;     // 128 f
constexpr size_t B_ZSE = 2688;     // 64 f
constexpr size_t B_ZSB = 2944;     // 64 f
constexpr size_t B_PFS = 3200;     // 64 f
constexpr size_t B_PTS = 4096;                                  // f32 [NP+1][3]
constexpr size_t B_Q   = 1204224;                               // bf16 [NP][64]
constexpr size_t B_U   = B_Q + (size_t)NP * DIM * 2;            // bf16 [NP+1][64]: v+pf
constexpr size_t B_KK  = B_U + (size_t)(NP + 1) * DIM * 2;      // u32 KP [(NP+1)][64]
constexpr size_t B_END = B_KK + (size_t)(NP + 1) * DIM * 4;     // 52,404,608

__device__ __forceinline__ ushort f2bf(float f) {
  union { float f; unsigned u; } v; v.f = f;
  unsigned u = v.u + 0x7fffu + ((v.u >> 16) & 1u);   // RNE
  return (ushort)(u >> 16);
}
__device__ __forceinline__ float bf2f(ushort b) {
  union { unsigned u; float f; } v; v.u = ((unsigned)b) << 16;
  return v.f;
}
__device__ __forceinline__ float u2f(unsigned u) {
  union { unsigned u; float f; } v; v.u = u; return v.f;
}

// hoist a [64][64] row-major weight into 8 bf16x8 fragments (B-operand)
__device__ __forceinline__ void load_wfrags(const float* __restrict__ ww, int lane,
                                            short8 wf[4][2]) {
  int co = lane & 15, g = lane >> 4;
#pragma unroll
  for (int tn = 0; tn < 4; ++tn)
#pragma unroll
    for (int kk = 0; kk < 2; ++kk) {
      const float* p = ww + (size_t)(co + 16 * tn) * DIM + kk * 32 + g * 8;
      short8 f;
#pragma unroll
      for (int j = 0; j < 8; ++j) f[j] = (short)f2bf(p[j]);
      wf[tn][kk] = f;
    }
}

__device__ __forceinline__ short8 pack_bf8(float4 a, float4 b) {
  short8 r;
  r[0] = (short)f2bf(a.x); r[1] = (short)f2bf(a.y);
  r[2] = (short)f2bf(a.z); r[3] = (short)f2bf(a.w);
  r[4] = (short)f2bf(b.x); r[5] = (short)f2bf(b.y);
  r[6] = (short)f2bf(b.z); r[7] = (short)f2bf(b.w);
  return r;
}

__global__ void k_init(char* __restrict__ wsb) {
  int t = threadIdx.x;
  double* s1 = (double*)(wsb + B_S1);
  double* s2 = (double*)(wsb + B_S2);
  if (t < 10) s1[t] = 0.0;
  if (t < 128) s2[t] = 0.0;
  if (t < 32)
    ((unsigned*)(wsb + B_U))[(size_t)NP * 32 + t] = 0u;   // u pad row (substituted anyway)
}

// padded f32 [NP+1][3] point table; row NP = (1e6,1e6,1e6)
__global__ __launch_bounds__(256) void k_pts(const float* __restrict__ pts,
                                             char* __restrict__ wsb) {
  int t = blockIdx.x * 256 + threadIdx.x;
  float* p3 = (float*)(wsb + B_PTS);
  if (t < NP * 3) p3[t] = pts[t];
  else if (t < NP * 3 + 3) p3[t] = 1e6f;
}

// point moments (9 doubles) + shadow count.  grid 512 — atomic contention-safe.
__global__ __launch_bounds__(256) void k_stats1(const int* __restrict__ nbr,
    char* __restrict__ wsb) {
  const float* p3 = (const float*)(wsb + B_PTS);
  double a[10] = {0, 0, 0, 0, 0, 0, 0, 0, 0, 0};
  int stride = gridDim.x * blockDim.x;
  for (int e = blockIdx.x * 256 + threadIdx.x; e < NP * KN; e += stride) {
    int idx = nbr[e];
    const float* pr = p3 + (size_t)idx * 3;
    float x = pr[0], y = pr[1], z = pr[2];
    a[9] += (idx >= NP) ? 1.0 : 0.0;
    a[0] += x; a[1] += y; a[2] += z;
    a[3] += (double)x * x; a[4] += (double)x * y; a[5] += (double)x * z;
    a[6] += (double)y * y; a[7] += (double)y * z; a[8] += (double)z * z;
  }
  __shared__ double red[256];
  double* s1 = (double*)(wsb + B_S1);
  for (int j = 0; j < 10; ++j) {
    red[threadIdx.x] = a[j];
    __syncthreads();
    for (int s = 128; s > 0; s >>= 1) {
      if (threadIdx.x < s) red[threadIdx.x] += red[threadIdx.x + s];
      __syncthreads();
    }
    if (threadIdx.x == 0) atomicAdd(&s1[j], red[0]);
    __syncthreads();
  }
}

// fold BN1 into affine on xyz
__global__ void k_fold1(const float* __restrict__ pw, const float* __restrict__ pb,
                        const float* __restrict__ pg, const float* __restrict__ pbeta,
                        char* __restrict__ wsb) {
  int c = threadIdx.x;
  if (c >= DIM) return;
  double* s1 = (double*)(wsb + B_S1);
  double inv = 1.0 / MS;
  double m0 = s1[0] * inv, m1 = s1[1] * inv, m2 = s1[2] * inv;
  double C00 = s1[3] * inv - m0 * m0, C01 = s1[4] * inv - m0 * m1;
  double C02 = s1[5] * inv - m0 * m2, C11 = s1[6] * inv - m1 * m1;
  double C12 = s1[7] * inv - m1 * m2, C22 = s1[8] * inv - m2 * m2;
  double w0 = pw[c * 3], w1 = pw[c * 3 + 1], w2 = pw[c * 3 + 2];
  double mean = w0 * m0 + w1 * m1 + w2 * m2 + (double)pb[c];
  double var = w0 * w0 * C00 + w1 * w1 * C11 + w2 * w2 * C22
             + 2.0 * (w0 * w1 * C01 + w0 * w2 * C02 + w1 * w2 * C12);
  if (var < 0.0) var = 0.0;
  double a = (double)pg[c] / sqrt(var + (double)BN_EPS_F);
  float4 o;
  o.x = (float)(w0 * a); o.y = (float)(w1 * a); o.z = (float)(w2 * a);
  o.w = (float)(((double)pb[c] - mean) * a + (double)pbeta[c]);
  ((float4*)(wsb + B_PWE))[c] = o;
}

// exact + bf16-path shadow w_lin; exact fp32 shadow pf; KP pad row
__global__ void k_shadow(const float* __restrict__ ww, const float* __restrict__ wb,
                         char* __restrict__ wsb) {
  __shared__ float pfs[64], pfb[64];
  int c = threadIdx.x;
  if (c >= DIM) return;
  float4 pwe = ((const float4*)(wsb + B_PWE))[c];
  float pf = fmaxf(fmaf(pwe.x, 1e6f, fmaf(pwe.y, 1e6f, fmaf(pwe.z, 1e6f, pwe.w))), 0.f);
  pfs[c] = pf;
  pfb[c] = bf2f(f2bf(pf));
  ((float*)(wsb + B_PFS))[c] = pf;
  ((unsigned*)(wsb + B_KK))[(size_t)NP * DIM + c] = ((unsigned)f2bf(pf) << 16);  // k=0
  __syncthreads();
  double ze = (double)wb[c], zb = (double)wb[c];
  for (int i = 0; i < DIM; ++i) {
    float w = ww[c * DIM + i];
    ze += (double)pfs[i] * (double)w;
    zb += (double)pfb[i] * (double)bf2f(f2bf(w));
  }
  ((float*)(wsb + B_ZSE))[c] = (float)ze;
  ((float*)(wsb + B_ZSB))[c] = (float)zb;
}

// MFMA q/kp/u builder: wave per 16-point tile (proven round-9 structure)
__global__ __launch_bounds__(256, 2) void k_qkv_mfma(const float* __restrict__ feats,
    const float* __restrict__ qw, const float* __restrict__ qb,
    const float* __restrict__ kw, const float* __restrict__ kb,
    const float* __restrict__ vw, const float* __restrict__ vb,
    char* __restrict__ wsb) {
  int tid = threadIdx.x, wid = tid >> 6, lane = tid & 63;
  int co = lane & 15, g = lane >> 4;
  short8 wfq[4][2], wfk[4][2], wfv[4][2];
  load_wfrags(qw, lane, wfq);
  load_wfrags(kw, lane, wfk);
  load_wfrags(vw, lane, wfv);
  float bq[4], bk[4], bv[4];
  float4 pwe4[4];
#pragma unroll
  for (int tn = 0; tn < 4; ++tn) {
    bq[tn] = qb[co + 16 * tn];
    bk[tn] = kb[co + 16 * tn];
    bv[tn] = vb[co + 16 * tn];
    pwe4[tn] = ((const float4*)(wsb + B_PWE))[co + 16 * tn];
  }
  const float* p3 = (const float*)(wsb + B_PTS);
  ushort* qt = (ushort*)(wsb + B_Q);
  ushort* ut = (ushort*)(wsb + B_U);
  unsigned* kpt = (unsigned*)(wsb + B_KK);
  const int NT = NP / 16;   // 6250
  for (int t = blockIdx.x * 4 + wid; t < NT; t += gridDim.x * 4) {
    const float* fr = feats + ((size_t)t * 16 + co) * DIM + g * 8;
    float4 f0 = *(const float4*)fr;
    float4 f1 = *(const float4*)(fr + 4);
    float4 f2 = *(const float4*)(fr + 32);
    float4 f3 = *(const float4*)(fr + 36);
    short8 a0 = pack_bf8(f0, f1);
    short8 a1 = pack_bf8(f2, f3);
    int nb = t * 16 + g * 4;
    float px[4], py[4], pz[4];
#pragma unroll
    for (int r = 0; r < 4; ++r) {
      const float* pr = p3 + (size_t)(nb + r) * 3;
      px[r] = pr[0]; py[r] = pr[1]; pz[r] = pr[2];
    }
    float pf[4][4];
#pragma unroll
    for (int tn = 0; tn < 4; ++tn)
#pragma unroll
      for (int r = 0; r < 4; ++r)
        pf[tn][r] = fmaxf(fmaf(pwe4[tn].x, px[r], fmaf(pwe4[tn].y, py[r],
                          fmaf(pwe4[tn].z, pz[r], pwe4[tn].w))), 0.f);
#pragma unroll
    for (int tn = 0; tn < 4; ++tn) {
      f32x4 acc = {bq[tn], bq[tn], bq[tn], bq[tn]};
      acc = __builtin_amdgcn_mfma_f32_16x16x32_bf16(a0, wfq[tn][0], acc, 0, 0, 0);
      acc = __builtin_amdgcn_mfma_f32_16x16x32_bf16(a1, wfq[tn][1], acc, 0, 0, 0);
#pragma unroll
      for (int r = 0; r < 4; ++r)
        qt[(size_t)(nb + r) * DIM + co + 16 * tn] = f2bf(acc[r]);
    }
#pragma unroll
    for (int tn = 0; tn < 4; ++tn) {
      f32x4 acc = {bk[tn], bk[tn], bk[tn], bk[tn]};
      acc = __builtin_amdgcn_mfma_f32_16x16x32_bf16(a0, wfk[tn][0], acc, 0, 0, 0);
      acc = __builtin_amdgcn_mfma_f32_16x16x32_bf16(a1, wfk[tn][1], acc, 0, 0, 0);
#pragma unroll
      for (int r = 0; r < 4; ++r)
        kpt[(size_t)(nb + r) * DIM + co + 16 * tn] =
            ((unsigned)f2bf(pf[tn][r]) << 16) | (unsigned)f2bf(acc[r]);
    }
#pragma unroll
    for (int tn = 0; tn < 4; ++tn) {
      f32x4 acc = {bv[tn], bv[tn], bv[tn], bv[tn]};
      acc = __builtin_amdgcn_mfma_f32_16x16x32_bf16(a0, wfv[tn][0], acc, 0, 0, 0);
      acc = __builtin_amdgcn_mfma_f32_16x16x32_bf16(a1, wfv[tn][1], acc, 0, 0, 0);
#pragma unroll
      for (int r = 0; r < 4; ++r)
        ut[(size_t)(nb + r) * DIM + co + 16 * tn] = f2bf(acc[r] + pf[tn][r]);
    }
  }
}

// ---- pipeline macros (per-lane vector loads only) ----
#define LOADN(SET, nn) {                                                      \
  const int4* p4_ = (const int4*)(nbr + (size_t)(nn) * KN);                   \
  int4 b0_ = p4_[0], b1_ = p4_[1], b2_ = p4_[2], b3_ = p4_[3];                \
  i##SET[0] = b0_.x; i##SET[1] = b0_.y; i##SET[2] = b0_.z; i##SET[3] = b0_.w; \
  i##SET[4] = b1_.x; i##SET[5] = b1_.y; i##SET[6] = b1_.z; i##SET[7] = b1_.w; \
  i##SET[8] = b2_.x; i##SET[9] = b2_.y; i##SET[10]= b2_.z; i##SET[11]= b2_.w; \
  i##SET[12]= b3_.x; i##SET[13]= b3_.y; i##SET[14]= b3_.z; i##SET[15]= b3_.w; }

// kp gather + q (stats2)
#define S2_LOADG(SET, nn) {                                                   \
  _Pragma("unroll") for (int k = 0; k < KN; ++k)                              \
    kp##SET[k] = kpt[(size_t)i##SET[k] * DIM + c];                            \
  q##SET = bf2f(qt[(size_t)(nn) * DIM + c]); }

// h-build + MFMA + stats only (NO z store)
#define S2_COMPUTE(SET, nn) {                                                 \
  _Pragma("unroll") for (int k = 0; k < KN; ++k) {                            \
    float kg_ = u2f(kp##SET[k] << 16);                                        \
    float pf_ = u2f(kp##SET[k] & 0xffff0000u);                                \
    hw[k * 64 + (c ^ ((k & 7) << 3))] = f2bf(fmaf(kg_, q##SET, pf_));         \
  }                                                                           \
  __builtin_amdgcn_wave_barrier();                                            \
  short8 a0_ = *(short8*)&hw[aoff0];                                          \
  short8 a1_ = *(short8*)&hw[aoff1];                                          \
  _Pragma("unroll") for (int tn = 0; tn < 4; ++tn) {                          \
    f32x4 acc_ = {wbv[tn], wbv[tn], wbv[tn], wbv[tn]};                        \
    acc_ = __builtin_amdgcn_mfma_f32_16x16x32_bf16(a0_, wf[tn][0], acc_,0,0,0);\
    acc_ = __builtin_amdgcn_mfma_f32_16x16x32_bf16(a1_, wf[tn][1], acc_,0,0,0);\
    _Pragma("unroll") for (int r = 0; r < 4; ++r) {                           \
      float zv_ = acc_[r];                                                    \
      s[tn] += zv_; ssq[tn] = fmaf(zv_, zv_, ssq[tn]); } }                    \
  __builtin_amdgcn_wave_barrier(); }

// BN2 stats via MFMA (no z).  grid MUST be 3125 x 256 (8 points/wave).
__global__ __launch_bounds__(256) void k_stats2(const int* __restrict__ nbr,
    const float* __restrict__ ww, const float* __restrict__ wbias,
    char* __restrict__ wsb) {
  __shared__ ushort hl[4][16 * 64];
  __shared__ float sred[4][64], ssred[4][64];
  int tid = threadIdx.x, wid = tid >> 6, lane = tid & 63, c = lane;
  short8 wf[4][2];
  load_wfrags(ww, lane, wf);
  float wbv[4];
#pragma unroll
  for (int tn = 0; tn < 4; ++tn) wbv[tn] = wbias[(lane & 15) + 16 * tn];
  const ushort* qt = (const ushort*)(wsb + B_Q);
  const unsigned* kpt = (const unsigned*)(wsb + B_KK);
  ushort* hw = hl[wid];
  int row = lane & 15, g = lane >> 4;
  int aoff0 = row * 64 + ((g * 8) ^ ((row & 7) << 3));
  int aoff1 = row * 64 + ((32 + g * 8) ^ ((row & 7) << 3));
  float s[4] = {0, 0, 0, 0}, ssq[4] = {0, 0, 0, 0};
  const int S = gridDim.x * 4;     // 12500
  int n = blockIdx.x * 4 + wid;

  int iA[KN], iB[KN];
  unsigned kpA[KN], kpB[KN];
  float qA, qB;

  LOADN(A, n)
  LOADN(B, n + S)
  S2_LOADG(A, n)
  for (int it = 0; it < 4; ++it) {
    S2_LOADG(B, n + S)
    if (it < 3) LOADN(A, n + 2 * S)
    S2_COMPUTE(A, n)
    if (it < 3) { S2_LOADG(A, n + 2 * S) LOADN(B, n + 3 * S) }
    S2_COMPUTE(B, n + S)
    n += 2 * S;
  }
#pragma unroll
  for (int t = 0; t < 4; ++t) {
    s[t] += __shfl_xor(s[t], 16);    s[t] += __shfl_xor(s[t], 32);
    ssq[t] += __shfl_xor(ssq[t], 16); ssq[t] += __shfl_xor(ssq[t], 32);
  }
  if (lane < 16) {
#pragma unroll
    for (int t = 0; t < 4; ++t) { sred[wid][lane + 16 * t] = s[t]; ssred[wid][lane + 16 * t] = ssq[t]; }
  }
  __syncthreads();
  if (tid < DIM) {
    double SS0 = 0.0, SS1 = 0.0;
    for (int w = 0; w < 4; ++w) { SS0 += (double)sred[w][tid]; SS1 += (double)ssred[w][tid]; }
    double* s2 = (double*)(wsb + B_S2);
    atomicAdd(&s2[tid], SS0);
    atomicAdd(&s2[DIM + tid], SS1);
  }
}

__global__ void k_fold2(const float* __restrict__ wg, const float* __restrict__ wbeta,
                        char* __restrict__ wsb) {
  int c = threadIdx.x;
  if (c >= DIM) return;
  double* s2 = (double*)(wsb + B_S2);
  double* s1 = (double*)(wsb + B_S1);
  double nsh = s1[9];
  double zse = (double)((float*)(wsb + B_ZSE))[c];
  double zsb = (double)((float*)(wsb + B_ZSB))[c];
  double S  = s2[c] + nsh * (zse - zsb);
  double SS = s2[DIM + c] + nsh * (zse * zse - zsb * zsb);
  double mean = S / MS;
  double var = SS / MS - mean * mean;
  if (var < 0.0) var = 0.0;
  double a = (double)wg[c] / sqrt(var + (double)BN_EPS_F);
  ((float*)(wsb + B_BN2))[c] = (float)a;
  ((float*)(wsb + B_BN2))[DIM + c] = (float)((double)wbeta[c] - mean * a);
}

// ---- recompute final: kp/u/sh/q captured at LOAD time (clobber-safe, round-5
// proven dataflow).  h via LDS + MFMA, zl transpose, softmax, u-weighted sum. ----
#define KF_LOADG(SET, nn) {                                                   \
  _Pragma("unroll") for (int k = 0; k < KN; ++k)                              \
    kp##SET[k] = kpt[(size_t)i##SET[k] * DIM + c];                            \
  _Pragma("unroll") for (int k = 0; k < KN; ++k)                              \
    uv##SET[k] = ut[(size_t)i##SET[k] * DIM + c];                             \
  sh##SET = 0u;                                                               \
  _Pragma("unroll") for (int k = 0; k < KN; ++k)                              \
    sh##SET |= (unsigned)(i##SET[k] >= NP) << k;                              \
  q##SET = bf2f(qt[(size_t)(nn) * DIM + c]); }

#define KF_COMPUTE(SET, nn) {                                                 \
  _Pragma("unroll") for (int k = 0; k < KN; ++k) {                            \
    float kg_ = u2f(kp##SET[k] << 16);                                        \
    float pf_ = u2f(kp##SET[k] & 0xffff0000u);                                \
    hw[k * 64 + (c ^ ((k & 7) << 3))] = f2bf(fmaf(kg_, q##SET, pf_));         \
  }                                                                           \
  __builtin_amdgcn_wave_barrier();                                            \
  short8 a0_ = *(short8*)&hw[aoff0];                                          \
  short8 a1_ = *(short8*)&hw[aoff1];                                          \
  _Pragma("unroll") for (int tn = 0; tn < 4; ++tn) {                          \
    f32x4 acc_ = {wbv[tn], wbv[tn], wbv[tn], wbv[tn]};                        \
    acc_ = __builtin_amdgcn_mfma_f32_16x16x32_bf16(a0_, wf[tn][0], acc_,0,0,0);\
    acc_ = __builtin_amdgcn_mfma_f32_16x16x32_bf16(a1_, wf[tn][1], acc_,0,0,0);\
    _Pragma("unroll") for (int r = 0; r < 4; ++r)                             \
      zw[(g * 4 + r) * 68 + (lane & 15) + 16 * tn] = acc_[r];                 \
  }                                                                           \
  __builtin_amdgcn_wave_barrier();                                            \
  float lg_[KN];                                                              \
  float m_ = 0.f;                                                             \
  _Pragma("unroll") for (int k = 0; k < KN; ++k) {                            \
    float lin_ = zw[k * 68 + c];                                              \
    if ((sh##SET >> k) & 1u) lin_ = zsec;                                     \
    float t_ = fmaxf(fmaf(lin_, fsc, fsh), 0.f);                              \
    lg_[k] = t_; m_ = fmaxf(m_, t_); }                                        \
  float se_ = 0.f;                                                            \
  _Pragma("unroll") for (int k = 0; k < KN; ++k) {                            \
    float e_ = __expf(lg_[k] - m_); lg_[k] = e_; se_ += e_; }                 \
  float rs_ = 1.0f / se_;                                                     \
  float att_ = 0.f;                                                           \
  _Pragma("unroll") for (int k = 0; k < KN; ++k) {                            \
    float u_ = ((sh##SET >> k) & 1u) ? pfsec : bf2f(uv##SET[k]);              \
    att_ = fmaf(u_, lg_[k] * rs_, att_); }                                    \
  __builtin_nontemporal_store(att_, out + (size_t)(nn) * DIM + c);            \
  __builtin_amdgcn_wave_barrier(); }

// grid MUST be 3125 x 256 (8 points/wave exactly)
__global__ __launch_bounds__(256) void k_final_rec(const int* __restrict__ nbr,
    const float* __restrict__ ww, const float* __restrict__ wbias,
    const char* __restrict__ wsb, float* __restrict__ out) {
  __shared__ ushort hl[4][16 * 64];
  __shared__ float zl[4][16 * 68];
  int tid = threadIdx.x, wid = tid >> 6, lane = tid & 63, c = lane;
  short8 wf[4][2];
  load_wfrags(ww, lane, wf);
  float wbv[4];
#pragma unroll
  for (int tn = 0; tn < 4; ++tn) wbv[tn] = wbias[(lane & 15) + 16 * tn];
  const ushort* qt = (const ushort*)(wsb + B_Q);
  const ushort* ut = (const ushort*)(wsb + B_U);
  const unsigned* kpt = (const unsigned*)(wsb + B_KK);
  const float* bn2 = (const float*)(wsb + B_BN2);
  float fsc = bn2[c], fsh = bn2[DIM + c];
  float zsec = ((const float*)(wsb + B_ZSE))[c];
  float pfsec = ((const float*)(wsb + B_PFS))[c];
  ushort* hw = hl[wid];
  float* zw = zl[wid];
  int row = lane & 15, g = lane >> 4;
  int aoff0 = row * 64 + ((g * 8) ^ ((row & 7) << 3));
  int aoff1 = row * 64 + ((32 + g * 8) ^ ((row & 7) << 3));
  const int S = gridDim.x * 4;     // 12500
  int n = blockIdx.x * 4 + wid;

  int iA[KN], iB[KN];
  unsigned kpA[KN], kpB[KN];
  ushort uvA[KN], uvB[KN];
  unsigned shA, shB;
  float qA, qB;

  LOADN(A, n)
  LOADN(B, n + S)
  KF_LOADG(A, n)
  for (int it = 0; it < 4; ++it) {
    KF_LOADG(B, n + S)
    if (it < 3) LOADN(A, n + 2 * S)
    KF_COMPUTE(A, n)
    if (it < 3) { KF_LOADG(A, n + 2 * S) LOADN(B, n + 3 * S) }
    KF_COMPUTE(B, n + S)
    n += 2 * S;
  }
}

extern "C" void kernel_launch(void* const* d_in, const int* in_sizes, int n_in,
                              void* d_out, int out_size, void* d_ws, size_t ws_size,
                              hipStream_t stream) {
  const float* pts   = (const float*)d_in[0];
  const int*   nbr   = (const int*)d_in[1];
  const float* feats = (const float*)d_in[2];
  const float* qw = (const float*)d_in[3];  const float* qb = (const float*)d_in[4];
  const float* kw = (const float*)d_in[5];  const float* kb = (const float*)d_in[6];
  const float* vw = (const float*)d_in[7];  const float* vb = (const float*)d_in[8];
  const float* pw = (const float*)d_in[9];  const float* pb = (const float*)d_in[10];
  const float* pg = (const float*)d_in[11]; const float* pbeta = (const float*)d_in[12];
  const float* www = (const float*)d_in[13]; const float* wb = (const float*)d_in[14];
  const float* wg  = (const float*)d_in[15]; const float* wbeta = (const float*)d_in[16];
  char* wsb = (char*)d_ws;
  float* out = (float*)d_out;

  hipLaunchKernelGGL(k_init,   dim3(1),    dim3(256), 0, stream, wsb);
  hipLaunchKernelGGL(k_pts,    dim3(1173), dim3(256), 0, stream, pts, wsb);
  hipLaunchKernelGGL(k_stats1, dim3(512),  dim3(256), 0, stream, nbr, wsb);
  hipLaunchKernelGGL(k_fold1,  dim3(1),    dim3(64),  0, stream, pw, pb, pg, pbeta, wsb);
  hipLaunchKernelGGL(k_shadow, dim3(1),    dim3(64),  0, stream, www, wb, wsb);
  hipLaunchKernelGGL(k_qkv_mfma, dim3(256), dim3(256), 0, stream,
                     feats, qw, qb, kw, kb, vw, vb, wsb);
  hipLaunchKernelGGL(k_stats2, dim3(3125), dim3(256), 0, stream, nbr, www, wb, wsb);
  hipLaunchKernelGGL(k_fold2,  dim3(1),    dim3(64),  0, stream, wg, wbeta, wsb);
  hipLaunchKernelGGL(k_final_rec, dim3(3125), dim3(256), 0, stream, nbr, www, wb, wsb, out);
}

// Round 14
// 280.528 us; speedup vs baseline: 1.7458x; 1.1790x over previous
//
#include <hip/hip_runtime.h>
#include <math.h>

#define NP 100000
#define KN 16
#define DIM 64
constexpr float BN_EPS_F = 1e-5f;
constexpr double MS = (double)NP * (double)KN;   // 1,600,000 samples

typedef __attribute__((ext_vector_type(8))) short short8;
typedef __attribute__((ext_vector_type(4))) float f32x4;
typedef __attribute__((ext_vector_type(2))) unsigned uint32x2;
typedef __attribute__((ext_vector_type(4))) unsigned uint32x4;

// ---- workspace layout (BYTE offsets) ----
constexpr size_t B_S1  = 0;        // 10 dbl
constexpr size_t B_PWE = 128;      // 64 * float4
constexpr size_t B_S2  = 1152;     // 128 dbl
constexpr size_t B_BN2 = 2176;     // 128 f
constexpr size_t B_ZSE = 2688;     // 64 f
constexpr size_t B_ZSB = 2944;     // 64 f
constexpr size_t B_PFS = 3200;     // 64 f
constexpr size_t B_PTS = 4096;                                  // f32 [NP+1][3]
constexpr size_t B_Q   = 1204224;                               // bf16 [NP][64]
constexpr size_t B_U   = B_Q + (size_t)NP * DIM * 2;            // bf16 [NP+1][64]: v+pf
constexpr size_t B_KK  = B_U + (size_t)(NP + 1) * DIM * 2;      // tier1: u32 KP; tier2: bf16 K
// tier 1: KP u32 [(NP+1)][64]
constexpr size_t B_Z1   = B_KK + (size_t)(NP + 1) * DIM * 4;
constexpr size_t B_END1 = B_Z1 + (size_t)NP * 2048;             // 257,204,608
// tier 2: K bf16 [(NP+1)][64]
constexpr size_t B_Z2   = B_KK + (size_t)(NP + 1) * DIM * 2;
constexpr size_t B_END2 = B_Z2 + (size_t)NP * 2048;             // 244,404,480 (proven fits)

__device__ __forceinline__ ushort f2bf(float f) {
  union { float f; unsigned u; } v; v.f = f;
  unsigned u = v.u + 0x7fffu + ((v.u >> 16) & 1u);   // RNE
  return (ushort)(u >> 16);
}
__device__ __forceinline__ float bf2f(ushort b) {
  union { unsigned u; float f; } v; v.u = ((unsigned)b) << 16;
  return v.f;
}
__device__ __forceinline__ float u2f(unsigned u) {
  union { unsigned u; float f; } v; v.u = u; return v.f;
}

// hoist a [64][64] row-major weight into 8 bf16x8 fragments (B-operand)
__device__ __forceinline__ void load_wfrags(const float* __restrict__ ww, int lane,
                                            short8 wf[4][2]) {
  int co = lane & 15, g = lane >> 4;
#pragma unroll
  for (int tn = 0; tn < 4; ++tn)
#pragma unroll
    for (int kk = 0; kk < 2; ++kk) {
      const float* p = ww + (size_t)(co + 16 * tn) * DIM + kk * 32 + g * 8;
      short8 f;
#pragma unroll
      for (int j = 0; j < 8; ++j) f[j] = (short)f2bf(p[j]);
      wf[tn][kk] = f;
    }
}

__device__ __forceinline__ short8 pack_bf8(float4 a, float4 b) {
  short8 r;
  r[0] = (short)f2bf(a.x); r[1] = (short)f2bf(a.y);
  r[2] = (short)f2bf(a.z); r[3] = (short)f2bf(a.w);
  r[4] = (short)f2bf(b.x); r[5] = (short)f2bf(b.y);
  r[6] = (short)f2bf(b.z); r[7] = (short)f2bf(b.w);
  return r;
}

__global__ void k_init(char* __restrict__ wsb) {
  int t = threadIdx.x;
  double* s1 = (double*)(wsb + B_S1);
  double* s2 = (double*)(wsb + B_S2);
  if (t < 10) s1[t] = 0.0;
  if (t < 128) s2[t] = 0.0;
  if (t < 32)
    ((unsigned*)(wsb + B_U))[(size_t)NP * 32 + t] = 0u;   // u pad row (substituted anyway)
}

// padded f32 [NP+1][3] point table; row NP = (1e6,1e6,1e6)
__global__ __launch_bounds__(256) void k_pts(const float* __restrict__ pts,
                                             char* __restrict__ wsb) {
  int t = blockIdx.x * 256 + threadIdx.x;
  float* p3 = (float*)(wsb + B_PTS);
  if (t < NP * 3) p3[t] = pts[t];
  else if (t < NP * 3 + 3) p3[t] = 1e6f;
}

// point moments (9 doubles) + shadow count
__global__ __launch_bounds__(256) void k_stats1(const int* __restrict__ nbr,
    char* __restrict__ wsb) {
  const float* p3 = (const float*)(wsb + B_PTS);
  double a[10] = {0, 0, 0, 0, 0, 0, 0, 0, 0, 0};
  int stride = gridDim.x * blockDim.x;
  for (int e = blockIdx.x * 256 + threadIdx.x; e < NP * KN; e += stride) {
    int idx = nbr[e];
    const float* pr = p3 + (size_t)idx * 3;
    float x = pr[0], y = pr[1], z = pr[2];
    a[9] += (idx >= NP) ? 1.0 : 0.0;
    a[0] += x; a[1] += y; a[2] += z;
    a[3] += (double)x * x; a[4] += (double)x * y; a[5] += (double)x * z;
    a[6] += (double)y * y; a[7] += (double)y * z; a[8] += (double)z * z;
  }
  __shared__ double red[256];
  double* s1 = (double*)(wsb + B_S1);
  for (int j = 0; j < 10; ++j) {
    red[threadIdx.x] = a[j];
    __syncthreads();
    for (int s = 128; s > 0; s >>= 1) {
      if (threadIdx.x < s) red[threadIdx.x] += red[threadIdx.x + s];
      __syncthreads();
    }
    if (threadIdx.x == 0) atomicAdd(&s1[j], red[0]);
    __syncthreads();
  }
}

// fold BN1 into affine on xyz
__global__ void k_fold1(const float* __restrict__ pw, const float* __restrict__ pb,
                        const float* __restrict__ pg, const float* __restrict__ pbeta,
                        char* __restrict__ wsb) {
  int c = threadIdx.x;
  if (c >= DIM) return;
  double* s1 = (double*)(wsb + B_S1);
  double inv = 1.0 / MS;
  double m0 = s1[0] * inv, m1 = s1[1] * inv, m2 = s1[2] * inv;
  double C00 = s1[3] * inv - m0 * m0, C01 = s1[4] * inv - m0 * m1;
  double C02 = s1[5] * inv - m0 * m2, C11 = s1[6] * inv - m1 * m1;
  double C12 = s1[7] * inv - m1 * m2, C22 = s1[8] * inv - m2 * m2;
  double w0 = pw[c * 3], w1 = pw[c * 3 + 1], w2 = pw[c * 3 + 2];
  double mean = w0 * m0 + w1 * m1 + w2 * m2 + (double)pb[c];
  double var = w0 * w0 * C00 + w1 * w1 * C11 + w2 * w2 * C22
             + 2.0 * (w0 * w1 * C01 + w0 * w2 * C02 + w1 * w2 * C12);
  if (var < 0.0) var = 0.0;
  double a = (double)pg[c] / sqrt(var + (double)BN_EPS_F);
  float4 o;
  o.x = (float)(w0 * a); o.y = (float)(w1 * a); o.z = (float)(w2 * a);
  o.w = (float)(((double)pb[c] - mean) * a + (double)pbeta[c]);
  ((float4*)(wsb + B_PWE))[c] = o;
}

// exact + bf16-path shadow w_lin; exact fp32 shadow pf; pad row of KK table
__global__ void k_shadow(const float* __restrict__ ww, const float* __restrict__ wb,
                         char* __restrict__ wsb, int kpmode) {
  __shared__ float pfs[64], pfb[64];
  int c = threadIdx.x;
  if (c >= DIM) return;
  float4 pwe = ((const float4*)(wsb + B_PWE))[c];
  float pf = fmaxf(fmaf(pwe.x, 1e6f, fmaf(pwe.y, 1e6f, fmaf(pwe.z, 1e6f, pwe.w))), 0.f);
  pfs[c] = pf;
  pfb[c] = bf2f(f2bf(pf));
  ((float*)(wsb + B_PFS))[c] = pf;
  if (kpmode)
    ((unsigned*)(wsb + B_KK))[(size_t)NP * DIM + c] = ((unsigned)f2bf(pf) << 16);  // k=0
  else
    ((ushort*)(wsb + B_KK))[(size_t)NP * DIM + c] = 0;                             // k=0
  __syncthreads();
  double ze = (double)wb[c], zb = (double)wb[c];
  for (int i = 0; i < DIM; ++i) {
    float w = ww[c * DIM + i];
    ze += (double)pfs[i] * (double)w;
    zb += (double)pfb[i] * (double)bf2f(f2bf(w));
  }
  ((float*)(wsb + B_ZSE))[c] = (float)ze;
  ((float*)(wsb + B_ZSB))[c] = (float)zb;
}

// MFMA q/k/u builder: wave per 16-point tile
template<bool KPMODE>
__global__ __launch_bounds__(256, 2) void k_qkv_mfma(const float* __restrict__ feats,
    const float* __restrict__ qw, const float* __restrict__ qb,
    const float* __restrict__ kw, const float* __restrict__ kb,
    const float* __restrict__ vw, const float* __restrict__ vb,
    char* __restrict__ wsb) {
  int tid = threadIdx.x, wid = tid >> 6, lane = tid & 63;
  int co = lane & 15, g = lane >> 4;
  short8 wfq[4][2], wfk[4][2], wfv[4][2];
  load_wfrags(qw, lane, wfq);
  load_wfrags(kw, lane, wfk);
  load_wfrags(vw, lane, wfv);
  float bq[4], bk[4], bv[4];
  float4 pwe4[4];
#pragma unroll
  for (int tn = 0; tn < 4; ++tn) {
    bq[tn] = qb[co + 16 * tn];
    bk[tn] = kb[co + 16 * tn];
    bv[tn] = vb[co + 16 * tn];
    pwe4[tn] = ((const float4*)(wsb + B_PWE))[co + 16 * tn];
  }
  const float* p3 = (const float*)(wsb + B_PTS);
  ushort* qt = (ushort*)(wsb + B_Q);
  ushort* ut = (ushort*)(wsb + B_U);
  ushort* kt = (ushort*)(wsb + B_KK);
  unsigned* kpt = (unsigned*)(wsb + B_KK);
  const int NT = NP / 16;   // 6250
  for (int t = blockIdx.x * 4 + wid; t < NT; t += gridDim.x * 4) {
    const float* fr = feats + ((size_t)t * 16 + co) * DIM + g * 8;
    float4 f0 = *(const float4*)fr;
    float4 f1 = *(const float4*)(fr + 4);
    float4 f2 = *(const float4*)(fr + 32);
    float4 f3 = *(const float4*)(fr + 36);
    short8 a0 = pack_bf8(f0, f1);
    short8 a1 = pack_bf8(f2, f3);
    int nb = t * 16 + g * 4;
    float px[4], py[4], pz[4];
#pragma unroll
    for (int r = 0; r < 4; ++r) {
      const float* pr = p3 + (size_t)(nb + r) * 3;
      px[r] = pr[0]; py[r] = pr[1]; pz[r] = pr[2];
    }
    float pf[4][4];
#pragma unroll
    for (int tn = 0; tn < 4; ++tn)
#pragma unroll
      for (int r = 0; r < 4; ++r)
        pf[tn][r] = fmaxf(fmaf(pwe4[tn].x, px[r], fmaf(pwe4[tn].y, py[r],
                          fmaf(pwe4[tn].z, pz[r], pwe4[tn].w))), 0.f);
#pragma unroll
    for (int tn = 0; tn < 4; ++tn) {
      f32x4 acc = {bq[tn], bq[tn], bq[tn], bq[tn]};
      acc = __builtin_amdgcn_mfma_f32_16x16x32_bf16(a0, wfq[tn][0], acc, 0, 0, 0);
      acc = __builtin_amdgcn_mfma_f32_16x16x32_bf16(a1, wfq[tn][1], acc, 0, 0, 0);
#pragma unroll
      for (int r = 0; r < 4; ++r)
        qt[(size_t)(nb + r) * DIM + co + 16 * tn] = f2bf(acc[r]);
    }
#pragma unroll
    for (int tn = 0; tn < 4; ++tn) {
      f32x4 acc = {bk[tn], bk[tn], bk[tn], bk[tn]};
      acc = __builtin_amdgcn_mfma_f32_16x16x32_bf16(a0, wfk[tn][0], acc, 0, 0, 0);
      acc = __builtin_amdgcn_mfma_f32_16x16x32_bf16(a1, wfk[tn][1], acc, 0, 0, 0);
#pragma unroll
      for (int r = 0; r < 4; ++r) {
        if (KPMODE)
          kpt[(size_t)(nb + r) * DIM + co + 16 * tn] =
              ((unsigned)f2bf(pf[tn][r]) << 16) | (unsigned)f2bf(acc[r]);
        else
          kt[(size_t)(nb + r) * DIM + co + 16 * tn] = f2bf(acc[r]);
      }
    }
#pragma unroll
    for (int tn = 0; tn < 4; ++tn) {
      f32x4 acc = {bv[tn], bv[tn], bv[tn], bv[tn]};
      acc = __builtin_amdgcn_mfma_f32_16x16x32_bf16(a0, wfv[tn][0], acc, 0, 0, 0);
      acc = __builtin_amdgcn_mfma_f32_16x16x32_bf16(a1, wfv[tn][1], acc, 0, 0, 0);
#pragma unroll
      for (int r = 0; r < 4; ++r)
        ut[(size_t)(nb + r) * DIM + co + 16 * tn] = f2bf(acc[r] + pf[tn][r]);
    }
  }
}

// ---- pipeline macros (per-lane vector loads only) ----
#define LOADN(SET, nn) {                                                      \
  const int4* p4_ = (const int4*)(nbr + (size_t)(nn) * KN);                   \
  int4 b0_ = p4_[0], b1_ = p4_[1], b2_ = p4_[2], b3_ = p4_[3];                \
  i##SET[0] = b0_.x; i##SET[1] = b0_.y; i##SET[2] = b0_.z; i##SET[3] = b0_.w; \
  i##SET[4] = b1_.x; i##SET[5] = b1_.y; i##SET[6] = b1_.z; i##SET[7] = b1_.w; \
  i##SET[8] = b2_.x; i##SET[9] = b2_.y; i##SET[10]= b2_.z; i##SET[11]= b2_.w; \
  i##SET[12]= b3_.x; i##SET[13]= b3_.y; i##SET[14]= b3_.z; i##SET[15]= b3_.w; }

// gather (pf,k) -> packed u32.  Tier1: one u32 gather.  Tier2: k gather + inline pf.
#define S2_LOADG(SET, nn) {                                                   \
  if constexpr (KPMODE) {                                                     \
    _Pragma("unroll") for (int k = 0; k < KN; ++k)                            \
      kp##SET[k] = kpt[(size_t)i##SET[k] * DIM + c];                          \
  } else {                                                                    \
    _Pragma("unroll") for (int k = 0; k < KN; ++k) {                          \
      int ik_ = i##SET[k];                                                    \
      unsigned kv_ = kt[(size_t)ik_ * DIM + c];                               \
      const float* pr_ = p3 + (size_t)ik_ * 3;                                \
      float px_ = pr_[0], py_ = pr_[1], pz_ = pr_[2];                         \
      float pf_ = fmaxf(fmaf(pwe.x, px_, fmaf(pwe.y, py_,                     \
                        fmaf(pwe.z, pz_, pwe.w))), 0.f);                      \
      kp##SET[k] = ((unsigned)f2bf(pf_) << 16) | kv_;                         \
    }                                                                         \
  }                                                                           \
  q##SET = bf2f(qt[(size_t)(nn) * DIM + c]); }

// h-build + MFMA + stats + transposed z store ([n][co][k] bf16) — NT stores
#define S2_COMPUTE(SET, nn) {                                                 \
  _Pragma("unroll") for (int k = 0; k < KN; ++k) {                            \
    float kg_ = u2f(kp##SET[k] << 16);                                        \
    float pf_ = u2f(kp##SET[k] & 0xffff0000u);                                \
    hw[k * 64 + (c ^ ((k & 7) << 3))] = f2bf(fmaf(kg_, q##SET, pf_));         \
  }                                                                           \
  __builtin_amdgcn_wave_barrier();                                            \
  short8 a0_ = *(short8*)&hw[aoff0];                                          \
  short8 a1_ = *(short8*)&hw[aoff1];                                          \
  char* zr_ = ztc + (size_t)(nn) * 2048 + g * 8;                              \
  _Pragma("unroll") for (int tn = 0; tn < 4; ++tn) {                          \
    f32x4 acc_ = {wbv[tn], wbv[tn], wbv[tn], wbv[tn]};                        \
    acc_ = __builtin_amdgcn_mfma_f32_16x16x32_bf16(a0_, wf[tn][0], acc_,0,0,0);\
    acc_ = __builtin_amdgcn_mfma_f32_16x16x32_bf16(a1_, wf[tn][1], acc_,0,0,0);\
    _Pragma("unroll") for (int r = 0; r < 4; ++r) {                           \
      float zv_ = acc_[r];                                                    \
      s[tn] += zv_; ssq[tn] = fmaf(zv_, zv_, ssq[tn]); }                      \
    uint32x2 w_;                                                              \
    w_.x = (unsigned)f2bf(acc_[0]) | ((unsigned)f2bf(acc_[1]) << 16);         \
    w_.y = (unsigned)f2bf(acc_[2]) | ((unsigned)f2bf(acc_[3]) << 16);         \
    __builtin_nontemporal_store(w_,                                           \
        (uint32x2*)(zr_ + ((lane & 15) + 16 * tn) * 32));                     \
  }                                                                           \
  __builtin_amdgcn_wave_barrier(); }

// BN2 stats via MFMA + z store.  grid MUST be 3125 x 256 (8 points/wave).
template<bool KPMODE>
__global__ __launch_bounds__(256) void k_stats2(const int* __restrict__ nbr,
    const float* __restrict__ ww, const float* __restrict__ wbias,
    char* __restrict__ wsb, char* __restrict__ ztc) {
  __shared__ ushort hl[4][16 * 64];
  __shared__ float sred[4][64], ssred[4][64];
  int tid = threadIdx.x, wid = tid >> 6, lane = tid & 63, c = lane;
  short8 wf[4][2];
  load_wfrags(ww, lane, wf);
  float wbv[4];
#pragma unroll
  for (int tn = 0; tn < 4; ++tn) wbv[tn] = wbias[(lane & 15) + 16 * tn];
  const ushort* qt = (const ushort*)(wsb + B_Q);
  const ushort* kt = (const ushort*)(wsb + B_KK);
  const unsigned* kpt = (const unsigned*)(wsb + B_KK);
  const float* p3 = (const float*)(wsb + B_PTS);
  float4 pwe = ((const float4*)(wsb + B_PWE))[c];
  ushort* hw = hl[wid];
  int row = lane & 15, g = lane >> 4;
  int aoff0 = row * 64 + ((g * 8) ^ ((row & 7) << 3));
  int aoff1 = row * 64 + ((32 + g * 8) ^ ((row & 7) << 3));
  float s[4] = {0, 0, 0, 0}, ssq[4] = {0, 0, 0, 0};
  const int S = gridDim.x * 4;     // 12500
  int n = blockIdx.x * 4 + wid;

  int iA[KN], iB[KN];
  unsigned kpA[KN], kpB[KN];
  float qA, qB;

  LOADN(A, n)
  LOADN(B, n + S)
  S2_LOADG(A, n)
  for (int it = 0; it < 4; ++it) {
    S2_LOADG(B, n + S)
    if (it < 3) LOADN(A, n + 2 * S)
    S2_COMPUTE(A, n)
    if (it < 3) { S2_LOADG(A, n + 2 * S) LOADN(B, n + 3 * S) }
    S2_COMPUTE(B, n + S)
    n += 2 * S;
  }
#pragma unroll
  for (int t = 0; t < 4; ++t) {
    s[t] += __shfl_xor(s[t], 16);    s[t] += __shfl_xor(s[t], 32);
    ssq[t] += __shfl_xor(ssq[t], 16); ssq[t] += __shfl_xor(ssq[t], 32);
  }
  if (lane < 16) {
#pragma unroll
    for (int t = 0; t < 4; ++t) { sred[wid][lane + 16 * t] = s[t]; ssred[wid][lane + 16 * t] = ssq[t]; }
  }
  __syncthreads();
  if (tid < DIM) {
    double SS0 = 0.0, SS1 = 0.0;
    for (int w = 0; w < 4; ++w) { SS0 += (double)sred[w][tid]; SS1 += (double)ssred[w][tid]; }
    double* s2 = (double*)(wsb + B_S2);
    atomicAdd(&s2[tid], SS0);
    atomicAdd(&s2[DIM + tid], SS1);
  }
}

__global__ void k_fold2(const float* __restrict__ wg, const float* __restrict__ wbeta,
                        char* __restrict__ wsb) {
  int c = threadIdx.x;
  if (c >= DIM) return;
  double* s2 = (double*)(wsb + B_S2);
  double* s1 = (double*)(wsb + B_S1);
  double nsh = s1[9];
  double zse = (double)((float*)(wsb + B_ZSE))[c];
  double zsb = (double)((float*)(wsb + B_ZSB))[c];
  double S  = s2[c] + nsh * (zse - zsb);
  double SS = s2[DIM + c] + nsh * (zse * zse - zsb * zsb);
  double mean = S / MS;
  double var = SS / MS - mean * mean;
  if (var < 0.0) var = 0.0;
  double a = (double)wg[c] / sqrt(var + (double)BN_EPS_F);
  ((float*)(wsb + B_BN2))[c] = (float)a;
  ((float*)(wsb + B_BN2))[DIM + c] = (float)((double)wbeta[c] - mean * a);
}

// ---- streaming final: NT z reads + u gather + softmax + NT out. grid 3125x256. ----
#define FS_LOADG(SET, nn) {                                                   \
  const char* zr_ = ztc + (size_t)(nn) * 2048 + c * 32;                       \
  *(uint32x4*)&zz##SET[0] = __builtin_nontemporal_load((const uint32x4*)zr_); \
  *(uint32x4*)&zz##SET[4] =                                                   \
      __builtin_nontemporal_load((const uint32x4*)(zr_ + 16));                \
  _Pragma("unroll") for (int k = 0; k < KN; ++k)                              \
    uv##SET[k] = ut[(size_t)i##SET[k] * DIM + c];                             \
  sh##SET = 0u;                                                               \
  _Pragma("unroll") for (int k = 0; k < KN; ++k)                              \
    sh##SET |= (unsigned)(i##SET[k] >= NP) << k; }

#define FS_COMPUTE(SET, nn) {                                                 \
  float lg_[KN];                                                              \
  float m_ = 0.f;                                                             \
  _Pragma("unroll") for (int k = 0; k < KN; ++k) {                            \
    float lin_ = bf2f((ushort)(zz##SET[k >> 1] >> ((k & 1) * 16)));           \
    if ((sh##SET >> k) & 1u) lin_ = zsec;                                     \
    float t_ = fmaxf(fmaf(lin_, fsc, fsh), 0.f);                              \
    lg_[k] = t_; m_ = fmaxf(m_, t_); }                                        \
  float se_ = 0.f;                                                            \
  _Pragma("unroll") for (int k = 0; k < KN; ++k) {                            \
    float e_ = __expf(lg_[k] - m_); lg_[k] = e_; se_ += e_; }                 \
  float rs_ = 1.0f / se_;                                                     \
  float att_ = 0.f;                                                           \
  _Pragma("unroll") for (int k = 0; k < KN; ++k) {                            \
    float u_ = ((sh##SET >> k) & 1u) ? pfsec : bf2f(uv##SET[k]);              \
    att_ = fmaf(u_, lg_[k] * rs_, att_); }                                    \
  __builtin_nontemporal_store(att_, out + (size_t)(nn) * DIM + c); }

__global__ __launch_bounds__(256) void k_final_str(const int* __restrict__ nbr,
    const char* __restrict__ wsb, const char* __restrict__ ztc,
    float* __restrict__ out) {
  int tid = threadIdx.x, wid = tid >> 6, c = tid & 63;
  const ushort* ut = (const ushort*)(wsb + B_U);
  const float* bn2 = (const float*)(wsb + B_BN2);
  float fsc = bn2[c], fsh = bn2[DIM + c];
  float zsec = ((const float*)(wsb + B_ZSE))[c];
  float pfsec = ((const float*)(wsb + B_PFS))[c];
  const int S = gridDim.x * 4;     // 12500
  int n = blockIdx.x * 4 + wid;

  int iA[KN], iB[KN];
  unsigned zzA[8] __attribute__((aligned(16)));
  unsigned zzB[8] __attribute__((aligned(16)));
  ushort uvA[KN], uvB[KN];
  unsigned shA, shB;

  LOADN(A, n)
  LOADN(B, n + S)
  FS_LOADG(A, n)
  for (int it = 0; it < 4; ++it) {
    FS_LOADG(B, n + S)
    if (it < 3) LOADN(A, n + 2 * S)
    FS_COMPUTE(A, n)
    if (it < 3) { FS_LOADG(A, n + 2 * S) LOADN(B, n + 3 * S) }
    FS_COMPUTE(B, n + S)
    n += 2 * S;
  }
}

extern "C" void kernel_launch(void* const* d_in, const int* in_sizes, int n_in,
                              void* d_out, int out_size, void* d_ws, size_t ws_size,
                              hipStream_t stream) {
  const float* pts   = (const float*)d_in[0];
  const int*   nbr   = (const int*)d_in[1];
  const float* feats = (const float*)d_in[2];
  const float* qw = (const float*)d_in[3];  const float* qb = (const float*)d_in[4];
  const float* kw = (const float*)d_in[5];  const float* kb = (const float*)d_in[6];
  const float* vw = (const float*)d_in[7];  const float* vb = (const float*)d_in[8];
  const float* pw = (const float*)d_in[9];  const float* pb = (const float*)d_in[10];
  const float* pg = (const float*)d_in[11]; const float* pbeta = (const float*)d_in[12];
  const float* www = (const float*)d_in[13]; const float* wb = (const float*)d_in[14];
  const float* wg  = (const float*)d_in[15]; const float* wbeta = (const float*)d_in[16];
  char* wsb = (char*)d_ws;
  float* out = (float*)d_out;

  const bool kpmode = (ws_size >= B_END1);      // tier 1 if the workspace allows
  char* zt = wsb + (kpmode ? B_Z1 : B_Z2);

  hipLaunchKernelGGL(k_init,   dim3(1),    dim3(256), 0, stream, wsb);
  hipLaunchKernelGGL(k_pts,    dim3(1173), dim3(256), 0, stream, pts, wsb);
  hipLaunchKernelGGL(k_stats1, dim3(512),  dim3(256), 0, stream, nbr, wsb);
  hipLaunchKernelGGL(k_fold1,  dim3(1),    dim3(64),  0, stream, pw, pb, pg, pbeta, wsb);
  hipLaunchKernelGGL(k_shadow, dim3(1),    dim3(64),  0, stream, www, wb, wsb, (int)kpmode);
  if (kpmode) {
    hipLaunchKernelGGL((k_qkv_mfma<true>), dim3(256),  dim3(256), 0, stream,
                       feats, qw, qb, kw, kb, vw, vb, wsb);
    hipLaunchKernelGGL((k_stats2<true>),   dim3(3125), dim3(256), 0, stream,
                       nbr, www, wb, wsb, zt);
  } else {
    hipLaunchKernelGGL((k_qkv_mfma<false>), dim3(256),  dim3(256), 0, stream,
                       feats, qw, qb, kw, kb, vw, vb, wsb);
    hipLaunchKernelGGL((k_stats2<false>),   dim3(3125), dim3(256), 0, stream,
                       nbr, www, wb, wsb, zt);
  }
  hipLaunchKernelGGL(k_fold2, dim3(1), dim3(64), 0, stream, wg, wbeta, wsb);
  hipLaunchKernelGGL(k_final_str, dim3(3125), dim3(256), 0, stream, nbr, wsb, zt, out);
}